// Round 8
// baseline (86.703 us; speedup 1.0000x reference)
//
#include <hip/hip_runtime.h>
#include <math.h>

#define NHEAD 8
#define HEAD_DIM 32
#define IMG_H 32
#define IMG_W 40
#define NPIX (IMG_H*IMG_W)
#define CMAX 160
#define NITER (CMAX/8)   // 20
#define FEAT (NHEAD*HEAD_DIM)

// ===== Geometry: LOCKED bit-exact numpy-fp32 emulation =====
// R27: register-LU (explicit scalars + pivot selects, arithmetic 1:1 with
// numpy chain) -> fusable without scratch demotion. PASSED, absmax 2^-10.

__device__ __forceinline__ void np_inv3x3_reg(const float* __restrict__ M, float inv[3][3]) {
#pragma clang fp contract(off)
    float a00=M[0], a01=M[1], a02=M[2];
    float a10=M[3], a11=M[4], a12=M[5];
    float a20=M[6], a21=M[7], a22=M[8];

    // ---- kk=0: pivot search (strictly-greater update, as numpy) ----
    const float c0 = fabsf(a00), c1 = fabsf(a10), c2 = fabsf(a20);
    const bool s1 = c1 > c0;
    const float cm = s1 ? c1 : c0;
    const bool s2 = c2 > cm;
    const bool q1 = s1 && !s2;      // pivot row 1
    const bool q2 = s2;             // pivot row 2 (q1,q2 mutually exclusive)
    {   // full row swap 0 <-> p0
        const float n0 = q2 ? a20 : (q1 ? a10 : a00);
        const float n1 = q2 ? a21 : (q1 ? a11 : a01);
        const float n2 = q2 ? a22 : (q1 ? a12 : a02);
        const float m0 = q1 ? a00 : a10, m1 = q1 ? a01 : a11, m2 = q1 ? a02 : a12;
        const float r0 = q2 ? a00 : a20, r1 = q2 ? a01 : a21, r2 = q2 ? a02 : a22;
        a00=n0; a01=n1; a02=n2;
        a10=m0; a11=m1; a12=m2;
        a20=r0; a21=r1; a22=r2;
    }
    const float rp0 = 1.0f / a00;
    a10 = a10 * rp0;
    a20 = a20 * rp0;
    a11 = a11 - a10*a01;
    a12 = a12 - a10*a02;
    a21 = a21 - a20*a01;
    a22 = a22 - a20*a02;

    // ---- kk=1: pivot search over rows 1,2 ----
    const bool sB = fabsf(a21) > fabsf(a11);
    {   // full row swap 1 <-> 2 (includes factored column 0, as numpy)
        const float t0 = sB ? a20 : a10, t1 = sB ? a21 : a11, t2 = sB ? a22 : a12;
        const float u0 = sB ? a10 : a20, u1 = sB ? a11 : a21, u2 = sB ? a12 : a22;
        a10=t0; a11=t1; a12=t2;
        a20=u0; a21=u1; a22=u2;
    }
    const float rp1 = 1.0f / a11;
    a21 = a21 * rp1;
    a22 = a22 - a21*a12;
    // kk=2: pivot is row 2, no swap, no elimination.

    // ---- solve A x = e_col for col=0,1,2 (constant-trip, unrolled) ----
    #pragma unroll
    for (int col = 0; col < 3; col++) {
        float b0 = (col==0) ? 1.0f : 0.0f;
        float b1 = (col==1) ? 1.0f : 0.0f;
        float b2 = (col==2) ? 1.0f : 0.0f;
        {   // apply piv[0]
            const float w0 = q2 ? b2 : (q1 ? b1 : b0);
            const float w1 = q1 ? b0 : b1;
            const float w2 = q2 ? b0 : b2;
            b0=w0; b1=w1; b2=w2;
        }
        {   // apply piv[1]
            const float x1 = sB ? b2 : b1;
            const float x2 = sB ? b1 : b2;
            b1=x1; b2=x2;
        }
        // forward substitution (i=1:kk=0; i=2:kk=0,1)
        b1 = b1 - a10*b0;
        b2 = b2 - a20*b0;
        b2 = b2 - a21*b1;
        // back substitution (kk=2: i=0,1; kk=1: i=0; kk=0)
        b2 = b2 / a22;
        b0 = b0 - a02*b2;
        b1 = b1 - a12*b2;
        b1 = b1 / a11;
        b0 = b0 - a01*b1;
        b0 = b0 / a00;
        inv[0][col]=b0; inv[1][col]=b1; inv[2][col]=b2;
    }
}

__device__ __forceinline__ void mm3_chain(const float A[3][3], const float B[3][3], float C[3][3]) {
#pragma clang fp contract(off)
    for (int i=0;i<3;i++)
        for (int j=0;j<3;j++) {
            float acc = A[i][0]*B[0][j];
            acc = acc + A[i][1]*B[1][j];
            acc = acc + A[i][2]*B[2][j];
            C[i][j] = acc;
        }
}
__device__ __forceinline__ void mm3_fma(const float A[3][3], const float B[3][3], float C[3][3]) {
#pragma clang fp contract(off)
    for (int i=0;i<3;i++)
        for (int j=0;j<3;j++) {
            float acc = A[i][0]*B[0][j];
            acc = __builtin_fmaf(A[i][1], B[1][j], acc);
            acc = __builtin_fmaf(A[i][2], B[2][j], acc);
            C[i][j] = acc;
        }
}
__device__ __forceinline__ float einsum_row(const float Fi[3], float x, float y) {
#pragma clang fp contract(off)
    float acc = Fi[0]*x;
    acc = acc + Fi[1]*y;
    acc = acc + Fi[2]*1.0f;
    return acc;
}

// ===== R29: R28 + hoisted row indices + explicit depth-2 load pipeline =====
// R28 analysis: kernel ~28 us (total 86.2 - ~58 us fixed harness overhead:
// 41 fill + ~17 gaps/memsets, calibrated from R25's visible 61-us kernel).
// 410 MB of L2 gather in 28 us = 42% of L2 peak -> concurrency-limited.
// Suspected serializer: per-iter s_cand LDS read heads the address chain
// (ds_read ~100cy -> addr -> 4 global loads ~250cy -> compute). Fix:
// (a) all 20 row indices pulled into registers right after the barrier
//     (static-index unrolled -> register-resident, no LDS in gather loop);
// (b) manual depth-2 rotation: iter i+1's 4 loads issue before iter i's
//     compute. Per-(head,iter) arithmetic order unchanged -> output
//     bit-identical to R28 (absmax must stay exactly 0.0009765625).

__global__ __launch_bounds__(256) void one2many_fused(
    const float* __restrict__ q, const float* __restrict__ k, const float* __restrict__ v,
    const float* __restrict__ K0, const float* __restrict__ K1,
    const float* __restrict__ R, const float* __restrict__ t,
    float* __restrict__ out)
{
#pragma clang fp contract(off)
    __shared__ int s_cand[CMAX];
    __shared__ int s_cnt;

    const int bx  = blockIdx.x;
    const int l   = (bx >> 3) + (bx & 7) * 160;   // XCD-contiguous bijection on [0,1280)
    const int tid = threadIdx.x;

    if (tid == 0) s_cnt = 0;

    const int w    = tid >> 6;          // wave index 0..3
    const int h0   = w;                 // first head
    const int h1   = w + 4;             // second head
    const int lane = tid & 63;
    const int grp  = lane >> 3;         // candidate sub-index within 8-group
    const int dj   = (lane & 7) << 2;   // dim offset 0,4,...,28

    // broadcast q loads: independent of geometry/scan -> issue early
    const float4 q4a = *(const float4*)(q + l*FEAT + h0*HEAD_DIM + dj);
    const float4 q4b = *(const float4*)(q + l*FEAT + h1*HEAD_DIM + dj);

    // ---- geometry: locked bit-exact chain, all threads, register-resident ----
    float slope, icpt; bool mode;
    {
        float i0[3][3], i1[3][3], A[3][3], B[3][3], T1[3][3], T2[3][3], Fm[3][3], Rm[3][3];
        np_inv3x3_reg(K0, i0);
        np_inv3x3_reg(K1, i1);
        for (int i=0;i<3;i++)
            for (int j=0;j<3;j++) { A[i][j] = i1[j][i]; Rm[i][j] = R[i*3+j]; }
        const float t0=t[0], t1=t[1], t2=t[2];
        B[0][0]=0.f;  B[0][1]=-t2;  B[0][2]=t1;
        B[1][0]=t2;   B[1][1]=0.f;  B[1][2]=-t0;
        B[2][0]=-t1;  B[2][1]=t0;   B[2][2]=0.f;
        mm3_chain(A,B,T1);      // noblas (swapaxes view)
        mm3_chain(T1,Rm,T2);    // T1 @ I
        mm3_fma(T2,i0,Fm);      // sgemm FMA
        const float xl = (float)(l % IMG_W);
        const float yl = (float)(l / IMG_W);
        const float la = einsum_row(Fm[0], xl, yl);
        const float lb = einsum_row(Fm[1], xl, yl);
        const float lc = einsum_row(Fm[2], xl, yl);
        mode = fabsf(lb) > fabsf(la);
        const float denom = mode ? lb : la;
        slope = (mode ? -la : -lb) / denom;
        icpt  = (-lc) / denom;
    }

    __syncthreads();   // s_cnt=0 visible

    // ---- candidate collection: identical fp32 band test ----
    for (int m = tid; m < NPIX; m += 256) {
        const float xm = (float)(m % IMG_W), ym = (float)(m / IMG_W);
        const float tin  = mode ? xm : ym;
        const float tchk = mode ? ym : xm;
        const float mu = slope * tin;
        const float cc = mu + icpt;
        const float hi = cc + 2.0f;
        const float lo = cc - 2.0f;
        if ((tchk < hi) && (tchk > lo) && m != 0) {
            int pos = atomicAdd(&s_cnt, 1);
            if (pos < CMAX) s_cand[pos] = m;
        }
    }
    __syncthreads();
    const int nc = min(s_cnt, CMAX);

    const float* kh0 = k + h0*HEAD_DIM + dj;
    const float* vh0 = v + h0*HEAD_DIM + dj;
    const float* kh1 = k + h1*HEAD_DIM + dj;
    const float* vh1 = v + h1*HEAD_DIM + dj;

    // ---- hoist ALL row indices to registers (no LDS in gather loop) ----
    size_t offs[NITER];
    bool   live[NITER];
    #pragma unroll
    for (int i = 0; i < NITER; i++) {
        const int ci = (i << 3) + grp;
        live[i] = (ci < nc);
        offs[i] = (size_t)s_cand[live[i] ? ci : 0] * FEAT;
    }

    // ---- single-pass QK+softmax+AV, depth-2 load pipeline ----
    float ax0=0.f, ay0=0.f, az0=0.f, aw0=0.f, ps0=0.f;
    float ax1=0.f, ay1=0.f, az1=0.f, aw1=0.f, ps1=0.f;

    float4 pk0 = *(const float4*)(kh0 + offs[0]);
    float4 pv0 = *(const float4*)(vh0 + offs[0]);
    float4 pk1 = *(const float4*)(kh1 + offs[0]);
    float4 pv1 = *(const float4*)(vh1 + offs[0]);

    #pragma unroll
    for (int i = 0; i < NITER; i++) {
        // current iteration's data (already in flight)
        const float4 k0 = pk0, v0 = pv0, k1 = pk1, v1 = pv1;
        // issue next iteration's loads before consuming current
        if (i + 1 < NITER) {
            pk0 = *(const float4*)(kh0 + offs[i+1]);
            pv0 = *(const float4*)(vh0 + offs[i+1]);
            pk1 = *(const float4*)(kh1 + offs[i+1]);
            pv1 = *(const float4*)(vh1 + offs[i+1]);
        }

        float p0 = q4a.x*k0.x;
        p0 = __builtin_fmaf(q4a.y, k0.y, p0);
        p0 = __builtin_fmaf(q4a.z, k0.z, p0);
        p0 = __builtin_fmaf(q4a.w, k0.w, p0);
        p0 += __shfl_xor(p0, 1);
        p0 += __shfl_xor(p0, 2);
        p0 += __shfl_xor(p0, 4);            // full dot, identical across 8-group

        float p1 = q4b.x*k1.x;
        p1 = __builtin_fmaf(q4b.y, k1.y, p1);
        p1 = __builtin_fmaf(q4b.z, k1.z, p1);
        p1 = __builtin_fmaf(q4b.w, k1.w, p1);
        p1 += __shfl_xor(p1, 1);
        p1 += __shfl_xor(p1, 2);
        p1 += __shfl_xor(p1, 4);

        const float e0 = live[i] ? __expf(p0 * 0.17677669529663687f) : 0.0f;
        const float e1 = live[i] ? __expf(p1 * 0.17677669529663687f) : 0.0f;
        ps0 += e0;
        ax0 = __builtin_fmaf(e0, v0.x, ax0);
        ay0 = __builtin_fmaf(e0, v0.y, ay0);
        az0 = __builtin_fmaf(e0, v0.z, az0);
        aw0 = __builtin_fmaf(e0, v0.w, aw0);
        ps1 += e1;
        ax1 = __builtin_fmaf(e1, v1.x, ax1);
        ay1 = __builtin_fmaf(e1, v1.y, ay1);
        az1 = __builtin_fmaf(e1, v1.z, az1);
        aw1 = __builtin_fmaf(e1, v1.w, aw1);
    }

    // ---- reduce over the 8 candidate groups (bits 3..5 of lane) ----
    #pragma unroll
    for (int o = 8; o <= 32; o <<= 1) {
        ax0 += __shfl_xor(ax0, o);
        ay0 += __shfl_xor(ay0, o);
        az0 += __shfl_xor(az0, o);
        aw0 += __shfl_xor(aw0, o);
        ps0 += __shfl_xor(ps0, o);
        ax1 += __shfl_xor(ax1, o);
        ay1 += __shfl_xor(ay1, o);
        az1 += __shfl_xor(az1, o);
        aw1 += __shfl_xor(aw1, o);
        ps1 += __shfl_xor(ps1, o);
    }

    if (lane < 8) {
        float4 r0, r1;
        if (nc > 0) {
            r0.x = ax0/ps0; r0.y = ay0/ps0; r0.z = az0/ps0; r0.w = aw0/ps0;
            r1.x = ax1/ps1; r1.y = ay1/ps1; r1.z = az1/ps1; r1.w = aw1/ps1;
        } else {
            r0.x = r0.y = r0.z = r0.w = 0.0f;
            r1.x = r1.y = r1.z = r1.w = 0.0f;
        }
        *(float4*)(out + l*FEAT + h0*HEAD_DIM + dj) = r0;
        *(float4*)(out + l*FEAT + h1*HEAD_DIM + dj) = r1;
    }
}

extern "C" void kernel_launch(void* const* d_in, const int* in_sizes, int n_in,
                              void* d_out, int out_size, void* d_ws, size_t ws_size,
                              hipStream_t stream) {
    const float* q  = (const float*)d_in[0];
    const float* k  = (const float*)d_in[1];
    const float* v  = (const float*)d_in[2];
    const float* K0 = (const float*)d_in[3];
    const float* K1 = (const float*)d_in[4];
    const float* R  = (const float*)d_in[5];
    const float* t  = (const float*)d_in[6];
    float* out = (float*)d_out;
    (void)d_ws; (void)ws_size;
    one2many_fused<<<NPIX, 256, 0, stream>>>(q, k, v, K0, K1, R, t, out);
}